// Round 7
// baseline (10010.198 us; speedup 1.0000x reference)
//
#include <hip/hip_runtime.h>
#include <stdint.h>

#define DEV static __device__ __forceinline__

DEV int imin(int a, int b){ return a < b ? a : b; }
DEV int imax(int a, int b){ return a > b ? a : b; }

// block-cooperative y[r] = dot(x, W[r,:]) + bias[r]; W row-major [R][K] fp32.
// wave w handles rows w, w+4, ...; lanes split the row (coalesced: lane j reads
// row[j], row[j+64], ...); wave shuffle-reduce; lane 0 writes y[r].
// Ends with __syncthreads(); y must not alias x.
DEV void gemv(const float* x, const float* W, const float* bias, float* y, int R, int K){
  int ln = threadIdx.x & 63, wv = threadIdx.x >> 6;
  for(int r = wv; r < R; r += 4){
    const float* row = W + (size_t)r * K;
    float p = 0.f;
    for(int j = ln; j < K; j += 64) p += x[j] * row[j];
    for(int off = 32; off > 0; off >>= 1) p += __shfl_down(p, off, 64);
    if(ln == 0) y[r] = p + bias[r];
  }
  __syncthreads();
}

DEV float bsum256(float v, float* buf){
  int t = threadIdx.x;
  buf[t] = v; __syncthreads();
  for(int st = 128; st > 0; st >>= 1){
    if(t < st) buf[t] += buf[t + st];
    __syncthreads();
  }
  float r = buf[0];
  __syncthreads();
  return r;
}

DEV float lnorm(float r, const float* g, const float* b, int off, float* buf){
  float m = bsum256(r, buf) * (1.f/256.f);
  float d = r - m;
  float v = bsum256(d*d, buf) * (1.f/256.f);
  return d * rsqrtf(v + 1e-5f) * g[off + threadIdx.x] + b[off + threadIdx.x];
}

// traj head: qn (LDS,256) -> 512 relu -> 11 outs; writes fp32 tp + fp32 out slot
DEV void traj_head(const float* qn,
                   const float* tw1, const float* tb1, const float* tw2, const float* tb2,
                   float* hb, float* y11, float* tp, float* out, int slot, int qi){
  int t = threadIdx.x;
  gemv(qn, tw1, tb1, hb, 512, 256);
  hb[t]     = fmaxf(0.f, hb[t]);
  hb[t+256] = fmaxf(0.f, hb[t+256]);
  __syncthreads();
  gemv(hb, tw2, tb2, y11, 11, 512);
  if(t < 11){
    float s = y11[t];
    tp[qi*11 + t] = s;
    out[(slot*128 + qi)*11 + t] = s;
  }
  __syncthreads();
}

// ---- transpose features (e, C, HW) -> FT[e][pos][c] fp32 (round-3 body) ----
__global__ __launch_bounds__(256) void k_tr(const float* feat, float* FT){
  int bid = blockIdx.x;
  int cc = bid & 3; int rest = bid >> 2;
  int pch = rest % 160; int e = rest / 160;
  __shared__ float tile[64][65];
  int t = threadIdx.x;
  for(int it = 0; it < 16; it++){
    int c = it*4 + (t >> 6);
    int p = t & 63;
    tile[p][c] = feat[((size_t)(e*256 + cc*64 + c))*10240 + pch*64 + p];
  }
  __syncthreads();
  for(int it = 0; it < 16; it++){
    int p = it*4 + (t >> 6);
    int c = t & 63;
    FT[((size_t)(e*10240 + pch*64 + p))*256 + cc*64 + c] = tile[p][c];
  }
}

// ---- init: q0 = queries, traj head slot0, sa-qkv layer0, zero acc ----
__global__ __launch_bounds__(256) void k_init(const float* queries,
    const float* tw1, const float* tb1, const float* tw2, const float* tb2,
    const float* saw, const float* sab,
    float* q, float* tp, float* qkv, float* acc, float* out){
  __shared__ float qn[256]; __shared__ float hb[512]; __shared__ float y11[16]; __shared__ float yy[768];
  int t = threadIdx.x, qi = blockIdx.x;
  float v = queries[qi*256 + t];
  qn[t] = v; q[qi*256 + t] = v;
  __syncthreads();
  traj_head(qn, tw1, tb1, tw2, tb2, hb, y11, tp, out, 0, qi);
  gemv(qn, saw, sab, yy, 768, 256);
  for(int r2 = 0; r2 < 3; r2++){
    int c = t + 256*r2;
    qkv[qi*768 + c] = yy[c];
  }
  acc[qi*256 + t] = 0.f;
}

// ---- sampling: block=(query,image), thread=channel; atomicAdd into acc (round-3 body, fp32) ----
__global__ __launch_bounds__(256) void k_sample(const float* FT, const float* feat, int use_ft,
    const float* cal, const float* ego, const float* tp, float* acc){
  int t = threadIdx.x;
  int qi = blockIdx.x & 127, e = blockIdx.x >> 7;
  int ci = e >> 1, tt = e & 1;
  __shared__ float tps[11];
  __shared__ float spx[152], spy[152];
  __shared__ int sval[152];
  if(t < 11) tps[t] = tp[qi*11 + t];
  __syncthreads();
  if(t < 150){
    float dt = ego[tt*4 + 3] - ego[7];
    int face = t/25, rr = t%25, ii = rr/5, jj = rr%5;
    float av = -1.f + 0.5f*ii, bv = -1.f + 0.5f*jj;
    float sg = (face & 1) ? 1.f : -1.f; int dim = face >> 1;
    float ux = (dim == 0) ? sg : av;
    float uy = (dim == 0) ? av : ((dim == 1) ? sg : bv);
    float uz = (dim == 2) ? sg : bv;
    float lx = ux*tps[8], ly = uy*tps[9], lz = uz*tps[10];
    float yaw = tps[7];
    float cyw = cosf(yaw), syw = sinf(yaw);
    float rx = lx*cyw - ly*syw, ry = lx*syw + ly*cyw;
    float dt2 = 0.5f*dt*dt;
    float cxx = tps[0] + tps[3]*dt + tps[5]*dt2;
    float cyy = tps[1] + tps[4]*dt + tps[6]*dt2;
    float wx = rx + cxx, wy = ry + cyy, wz = lz + tps[2];
    float ex = ego[tt*4], ey = ego[tt*4 + 1], eyaw = ego[tt*4 + 2];
    float ce = cosf(eyaw), se = sinf(eyaw);
    float pxr = wx - ex, pyr = wy - ey;
    float gx = pxr*ce + pyr*se, gy = -pxr*se + pyr*ce;
    float fx = cal[ci*8],    fy = cal[ci*8+1];
    float cx0 = cal[ci*8+2], cy0 = cal[ci*8+3];
    float tx = cal[ci*8+4], ty = cal[ci*8+5];
    float tz = cal[ci*8+6], cw = cal[ci*8+7];
    float cc = cosf(cw), sc = sinf(cw);
    float pxc = gx - tx, pyc = gy - ty, pzc = wz - tz;
    float zc = pxc*cc + pyc*sc;
    float left = -pxc*sc + pyc*cc;
    float xc = -left, yc = -pzc;
    float zs = fmaxf(zc, 0.1f);
    float u = fx*xc/zs + cx0, vv = fy*yc/zs + cy0;
    bool val = (zc > 0.1f) && (u >= 0.f) && (u < 1.f) && (vv >= 0.f) && (vv < 1.f);
    spx[t] = u*159.f; spy[t] = vv*63.f;
    sval[t] = val ? 1 : 0;
  }
  __syncthreads();
  float a = 0.f;
  if(use_ft){
    const float* base = FT + (size_t)e*10240*256 + t;
    for(int p = 0; p < 150; p++){
      if(!sval[p]) continue;
      float px = spx[p], py = spy[p];
      float x0f = floorf(px), y0f = floorf(py);
      float wxf = px - x0f, wyf = py - y0f;
      int x0 = imin(imax((int)x0f, 0), 159), y0 = imin(imax((int)y0f, 0), 63);
      int x1 = imin(x0 + 1, 159), y1 = imin(y0 + 1, 63);
      float w00 = (1.f-wxf)*(1.f-wyf), w01 = wxf*(1.f-wyf), w10 = (1.f-wxf)*wyf, w11 = wxf*wyf;
      const float* r0 = base + (size_t)(y0*160)*256;
      const float* r1 = base + (size_t)(y1*160)*256;
      a += w00*r0[x0*256] + w01*r0[x1*256] + w10*r1[x0*256] + w11*r1[x1*256];
    }
  } else {
    const float* pc = feat + ((size_t)e*256 + t)*10240;
    for(int p = 0; p < 150; p++){
      if(!sval[p]) continue;
      float px = spx[p], py = spy[p];
      float x0f = floorf(px), y0f = floorf(py);
      float wxf = px - x0f, wyf = py - y0f;
      int x0 = imin(imax((int)x0f, 0), 159), y0 = imin(imax((int)y0f, 0), 63);
      int x1 = imin(x0 + 1, 159), y1 = imin(y0 + 1, 63);
      float w00 = (1.f-wxf)*(1.f-wyf), w01 = wxf*(1.f-wyf), w10 = (1.f-wxf)*wyf, w11 = wxf*wyf;
      a += w00*pc[y0*160 + x0] + w01*pc[y0*160 + x1]
         + w10*pc[y1*160 + x0] + w11*pc[y1*160 + x1];
    }
  }
  atomicAdd(&acc[qi*256 + t], a);
}

// ---- feature MLP + cross-attn K/V rows ----
__global__ __launch_bounds__(256) void k_memkv(const float* acc,
    const float* fw1, const float* fb1, const float* fw2, const float* fb2,
    const float* caw, const float* cab, int li, float* kv){
  __shared__ float agg[256]; __shared__ float h[512]; __shared__ float memr[256]; __shared__ float yy[512];
  int t = threadIdx.x, qi = blockIdx.x;
  agg[t] = acc[qi*256 + t] * (1.f/1800.f);
  __syncthreads();
  gemv(agg, fw1, fb1, h, 512, 256);
  h[t]     = fmaxf(0.f, h[t]);
  h[t+256] = fmaxf(0.f, h[t+256]);
  __syncthreads();
  gemv(h, fw2, fb2, memr, 256, 512);
  // CA K,V = caw rows 256..767 (contiguous block), bias 256..767
  gemv(memr, caw + (size_t)li*196608 + 65536, cab + li*768 + 256, yy, 512, 256);
  kv[qi*512 + t]       = yy[t];
  kv[qi*512 + 256 + t] = yy[256 + t];
}

// ---- self-attn + out-proj + LN1 + cross-attn q-proj (round-3 attention body) ----
__global__ __launch_bounds__(256) void k_sa(const float* q, const float* qkv,
    const float* sow, const float* sob, const float* n1g, const float* n1b,
    const float* caw, const float* cab, int li,
    float* qs, float* qq){
  __shared__ float qv[256]; __shared__ float s[1024]; __shared__ float o[256];
  __shared__ float buf[256]; __shared__ float yy[256];
  int t = threadIdx.x, qi = blockIdx.x;
  qv[t] = qkv[qi*768 + t];
  __syncthreads();
  for(int rep = 0; rep < 4; rep++){
    int idx = t + rep*256; int hh = idx >> 7, k = idx & 127;
    const float* kr = qkv + k*768 + 256 + hh*32;
    const float* qr = qv + hh*32;
    float sa = 0.f;
    for(int i = 0; i < 32; i++) sa += qr[i]*kr[i];
    s[idx] = sa * 0.1767766952966369f;
  }
  __syncthreads();
  if(t < 8){
    float m = -1e30f;
    for(int k = 0; k < 128; k++) m = fmaxf(m, s[t*128 + k]);
    float ss = 0.f;
    for(int k = 0; k < 128; k++){ float e2 = __expf(s[t*128 + k] - m); s[t*128 + k] = e2; ss += e2; }
    float inv = 1.f / ss;
    for(int k = 0; k < 128; k++) s[t*128 + k] *= inv;
  }
  __syncthreads();
  { int hh = t >> 5;
    float oa = 0.f;
    for(int k = 0; k < 128; k++) oa += s[hh*128 + k] * qkv[k*768 + 512 + t];
    o[t] = oa; }
  __syncthreads();
  gemv(o, sow + (size_t)li*65536, sob + li*256, yy, 256, 256);
  float r = q[qi*256 + t] + yy[t];
  float y = lnorm(r, n1g, n1b, li*256, buf);
  qs[qi*256 + t] = y;
  o[t] = y;
  __syncthreads();
  gemv(o, caw + (size_t)li*196608, cab + li*768, yy, 256, 256);
  qq[qi*256 + t] = yy[t];
}

// ---- cross-attn + proj + LN2 + FFN + LN3 + traj head + next sa-qkv + acc clear ----
__global__ __launch_bounds__(256) void k_ca(const float* qs, const float* qq, const float* kv,
    const float* cow, const float* cob, const float* n2g, const float* n2b,
    const float* l1w, const float* l1b, const float* l2w, const float* l2b,
    const float* n3g, const float* n3b,
    const float* tw1, const float* tb1, const float* tw2, const float* tb2,
    const float* saw, const float* sab, int li, int have_next,
    float* qout, float* qkv, float* tp, float* acc, float* out){
  __shared__ float qv[256]; __shared__ float s[1024]; __shared__ float o[256];
  __shared__ float q2[256]; __shared__ float h[512]; __shared__ float buf[256];
  __shared__ float yy[768]; __shared__ float y11[16];
  int t = threadIdx.x, qi = blockIdx.x;
  qv[t] = qq[qi*256 + t];
  __syncthreads();
  for(int rep = 0; rep < 4; rep++){
    int idx = t + rep*256; int hh = idx >> 7, k = idx & 127;
    const float* kr = kv + k*512 + hh*32;
    const float* qr = qv + hh*32;
    float sa = 0.f;
    for(int i = 0; i < 32; i++) sa += qr[i]*kr[i];
    s[idx] = sa * 0.1767766952966369f;
  }
  __syncthreads();
  if(t < 8){
    float m = -1e30f;
    for(int k = 0; k < 128; k++) m = fmaxf(m, s[t*128 + k]);
    float ss = 0.f;
    for(int k = 0; k < 128; k++){ float e2 = __expf(s[t*128 + k] - m); s[t*128 + k] = e2; ss += e2; }
    float inv = 1.f / ss;
    for(int k = 0; k < 128; k++) s[t*128 + k] *= inv;
  }
  __syncthreads();
  { int hh = t >> 5;
    float oa = 0.f;
    for(int k = 0; k < 128; k++) oa += s[hh*128 + k] * kv[k*512 + 256 + t];
    o[t] = oa; }
  __syncthreads();
  gemv(o, cow + (size_t)li*65536, cob + li*256, yy, 256, 256);
  float r = qs[qi*256 + t] + yy[t];
  float y = lnorm(r, n2g, n2b, li*256, buf);
  q2[t] = y;
  __syncthreads();
  gemv(q2, l1w + (size_t)li*131072, l1b + li*512, h, 512, 256);
  h[t]     = fmaxf(0.f, h[t]);
  h[t+256] = fmaxf(0.f, h[t+256]);
  __syncthreads();
  gemv(h, l2w + (size_t)li*131072, l2b + li*256, yy, 256, 512);
  float r3 = q2[t] + yy[t];
  float y3 = lnorm(r3, n3g, n3b, li*256, buf);
  qout[qi*256 + t] = y3;
  q2[t] = y3;
  __syncthreads();
  traj_head(q2, tw1, tb1, tw2, tb2, h, y11, tp, out, li + 1, qi);
  if(have_next){
    int ln = li + 1;
    gemv(q2, saw + (size_t)ln*196608, sab + ln*768, yy, 768, 256);
    for(int r2 = 0; r2 < 3; r2++){
      int c = t + 256*r2;
      qkv[qi*768 + c] = yy[c];
    }
  }
  acc[qi*256 + t] = 0.f;
}

extern "C" void kernel_launch(void* const* d_in, const int* in_sizes, int n_in,
                              void* d_out, int out_size, void* d_ws, size_t ws_size,
                              hipStream_t stream){
  const float* feat    = (const float*)d_in[0];
  const float* calib   = (const float*)d_in[1];
  const float* ego     = (const float*)d_in[2];
  const float* queries = (const float*)d_in[3];
  // d_in[4] = query_pos (unused by reference)
  const float* tw1 = (const float*)d_in[5];  const float* tb1 = (const float*)d_in[6];
  const float* tw2 = (const float*)d_in[7];  const float* tb2 = (const float*)d_in[8];
  const float* fw1 = (const float*)d_in[9];  const float* fb1 = (const float*)d_in[10];
  const float* fw2 = (const float*)d_in[11]; const float* fb2 = (const float*)d_in[12];
  const float* saw = (const float*)d_in[13]; const float* sab = (const float*)d_in[14];
  const float* sow = (const float*)d_in[15]; const float* sob = (const float*)d_in[16];
  const float* caw = (const float*)d_in[17]; const float* cab = (const float*)d_in[18];
  const float* cow = (const float*)d_in[19]; const float* cob = (const float*)d_in[20];
  const float* l1w = (const float*)d_in[21]; const float* l1b = (const float*)d_in[22];
  const float* l2w = (const float*)d_in[23]; const float* l2b = (const float*)d_in[24];
  const float* n1g = (const float*)d_in[25]; const float* n1b = (const float*)d_in[26];
  const float* n2g = (const float*)d_in[27]; const float* n2b = (const float*)d_in[28];
  const float* n3g = (const float*)d_in[29]; const float* n3b = (const float*)d_in[30];
  float* out = (float*)d_out;

  // round-3 workspace layout (first 16 floats reserved)
  float* ws   = (float*)d_ws;
  float* q    = ws + 16;               // 32768
  float* qs   = ws + 32784;            // 32768
  float* tp   = ws + 65552;            // 1408 (pad 1536)
  float* qkv  = ws + 67088;            // 98304
  float* kv   = ws + 165392;           // 65536
  float* qq   = ws + 230928;           // 32768
  float* acc  = ws + 263696;           // 32768 -> end 296464 floats
  float* FT   = ws + 296464;           // 12*10240*256 floats
  size_t need = (size_t)296464*4 + (size_t)12*10240*256*4;
  int use_ft = (ws_size >= need) ? 1 : 0;

  if(use_ft) k_tr<<<12*160*4, 256, 0, stream>>>(feat, FT);
  k_init<<<128, 256, 0, stream>>>(queries, tw1, tb1, tw2, tb2, saw, sab, q, tp, qkv, acc, out);
  for(int li = 0; li < 6; li++){
    k_sample<<<1536, 256, 0, stream>>>(FT, feat, use_ft, calib, ego, tp, acc);
    k_memkv<<<128, 256, 0, stream>>>(acc, fw1, fb1, fw2, fb2, caw, cab, li, kv);
    k_sa<<<128, 256, 0, stream>>>(q, qkv, sow, sob, n1g, n1b, caw, cab, li, qs, qq);
    int hn = (li < 5) ? 1 : 0;
    k_ca<<<128, 256, 0, stream>>>(qs, qq, kv, cow, cob, n2g, n2b,
                                  l1w, l1b, l2w, l2b, n3g, n3b,
                                  tw1, tb1, tw2, tb2, saw, sab, li, hn,
                                  q, qkv, tp, acc, out);
  }
  (void)in_sizes; (void)n_in; (void)out_size;
}